// Round 5
// baseline (186.664 us; speedup 1.0000x reference)
//
#include <hip/hip_runtime.h>
#include <math.h>

// Shapes (fixed by the problem)
#define Hn 8
#define Sn 1024
#define Dn 64
#define KG 10

// Bias tables: dist in [0,10), energy in [0,5)
#define TN 2048
#define RD 10.25f
#define RE 5.125f

typedef __attribute__((ext_vector_type(8))) short bf16x8;
typedef __attribute__((ext_vector_type(4))) float f32x4;
typedef __attribute__((ext_vector_type(4))) _Float16 h16x4;
typedef unsigned short u16;
typedef unsigned int u32;

__device__ inline float bf2f(u16 u) {
    union { u32 i; float f; } v;
    v.i = ((u32)u) << 16;
    return v.f;
}

__device__ inline u16 f2bf(float f) {
    union { float f; u32 i; } v;
    v.f = f;
    u32 i = v.i;
    return (u16)((i + 0x7FFFu + ((i >> 16) & 1u)) >> 16);   // RNE
}

__device__ inline u16 f2h_bits(float f) {
    union { _Float16 h; u16 u; } cv;
    cv.h = (_Float16)f;                                     // v_cvt_f16_f32, RNE
    return cv.u;
}

// ---------------------------------------------------------------------------
// RBF (10 gaussians) -> 10x10 MLP (exact gelu) -> scalar, all f32.
// ---------------------------------------------------------------------------
__device__ float bias_eval(float x,
                           const float* __restrict__ mu, const float* __restrict__ sg,
                           const float* __restrict__ bb,
                           const float* __restrict__ W1, const float* __restrict__ b1,
                           const float* __restrict__ W2, const float* __restrict__ b2) {
    const float inv_s2pi = 0.39894228040143267794f;
    float psi[KG];
#pragma unroll
    for (int k = 0; k < KG; k++) {
        float s = sg[k];
        float z = (x + bb[k] - mu[k]) / s;
        psi[k] = __expf(-0.5f * z * z) * (inv_s2pi / s);
    }
    float out = b2[0];
#pragma unroll
    for (int l = 0; l < KG; l++) {
        float a = b1[l];
#pragma unroll
        for (int k = 0; k < KG; k++) a += psi[k] * W1[l * KG + k];
        float g = 0.5f * a * (1.0f + erff(a * 0.70710678118654752440f));
        out += g * W2[l];
    }
    return out;
}

// ---------------------------------------------------------------------------
// Kernel A: interpolation tables. Entry i: lo16 = bf16(f(x_i)),
// hi16 = bf16(f(x_{i+1}) - f(x_i)). [0,TN) dist, [TN,2TN) energy.
// ---------------------------------------------------------------------------
__global__ __launch_bounds__(256) void build_tables_kernel(
    const float* __restrict__ muD, const float* __restrict__ sgD, const float* __restrict__ bD,
    const float* __restrict__ muE, const float* __restrict__ sgE, const float* __restrict__ bE,
    const float* __restrict__ W1, const float* __restrict__ b1,
    const float* __restrict__ W2, const float* __restrict__ b2,
    u32* __restrict__ tab)
{
    int id = blockIdx.x * 256 + threadIdx.x;   // 0 .. 4095
    int which = (id >= TN);
    int idx = id & (TN - 1);
    float h = (which ? RE : RD) / (float)TN;
    float x0 = idx * h;
    float v0, v1;
    if (which) {
        v0 = bias_eval(x0,     muE, sgE, bE, W1, b1, W2, b2);
        v1 = bias_eval(x0 + h, muE, sgE, bE, W1, b1, W2, b2);
    } else {
        v0 = bias_eval(x0,     muD, sgD, bD, W1, b1, W2, b2);
        v1 = bias_eval(x0 + h, muD, sgD, bD, W1, b1, W2, b2);
    }
    tab[id] = (u32)f2bf(v0) | ((u32)f2bf(v1 - v0) << 16);
}

// ---------------------------------------------------------------------------
// Kernel B: streaming prepass.
//  WGs [0,4096)     : bias condense — read D,E (f32) + mask, write
//                     Bb[h][q][k] = fp16( tabD(D) + tabE(E) ), masked -> -60.
//                     8 elems/thread, fully coalesced.
//  WGs [4096,5120)  : Q,K f32 -> bf16 (float4 granularity).
//  WGs [5120,7168)  : V -> bf16, transposed [h][d][s'] with MFMA k-perm:
//                     s' = t*32+q*8+j  <->  s = t*32+q*4+(j&3)+16*(j>>2).
// ---------------------------------------------------------------------------
__global__ __launch_bounds__(256) void prep_kernel(
    const float* __restrict__ Dm, const float* __restrict__ Em, const int* __restrict__ Mk,
    const float* __restrict__ Q, const float* __restrict__ K, const float* __restrict__ V,
    const u32* __restrict__ tab,
    u16* __restrict__ Bb, u16* __restrict__ Qb, u16* __restrict__ Kb, u16* __restrict__ VTi)
{
    __shared__ __align__(16) u32 sTab[2 * TN];   // 16 KB
    const int wg = blockIdx.x;
    const int tid = threadIdx.x;

    if (wg < 4096) {
        {   // stage tables: 1024 uint4 over 256 threads
            const uint4* g4 = (const uint4*)tab;
            uint4* s4 = (uint4*)sTab;
#pragma unroll
            for (int i = 0; i < 4; i++) s4[tid + 256 * i] = g4[tid + 256 * i];
        }
        __syncthreads();

        const float invhD = (float)TN / RD;
        const float invhE = (float)TN / RE;
        const size_t base = ((size_t)wg * 256 + tid) * 8;

        const float4 d0 = *(const float4*)(Dm + base);
        const float4 d1 = *(const float4*)(Dm + base + 4);
        const float4 e0 = *(const float4*)(Em + base);
        const float4 e1 = *(const float4*)(Em + base + 4);
        const int4   m0 = *(const int4*)(Mk + base);
        const int4   m1 = *(const int4*)(Mk + base + 4);

        const float dv[8] = {d0.x, d0.y, d0.z, d0.w, d1.x, d1.y, d1.z, d1.w};
        const float ev[8] = {e0.x, e0.y, e0.z, e0.w, e1.x, e1.y, e1.z, e1.w};
        const int   mv[8] = {m0.x, m0.y, m0.z, m0.w, m1.x, m1.y, m1.z, m1.w};

        u16 ob[8];
#pragma unroll
        for (int j = 0; j < 8; j++) {
            float tf = dv[j] * invhD;
            int i = min((int)tf, TN - 1);
            float fr = tf - (float)i;
            u32 p = sTab[i];
            float vD = fmaf(bf2f((u16)(p >> 16)), fr, bf2f((u16)p));

            tf = ev[j] * invhE;
            i = min((int)tf, TN - 1);
            fr = tf - (float)i;
            p = sTab[TN + i];
            float vE = fmaf(bf2f((u16)(p >> 16)), fr, bf2f((u16)p));

            float v = vD + vE;
            v = fminf(fmaxf(v, -60.f), 64.f);
            v = (mv[j] == 0) ? -60.f : v;
            ob[j] = f2h_bits(v);
        }
        *(uint4*)(Bb + base) = *(const uint4*)ob;
    } else if (wg < 5120) {
        int i = (wg - 4096) * 256 + tid;        // 0 .. 262143 float4 units
        int arr = i >> 17;                       // 0 = Q, 1 = K
        i &= (1 << 17) - 1;
        float4 v = ((const float4*)(arr ? K : Q))[i];
        ushort4 o;
        o.x = f2bf(v.x); o.y = f2bf(v.y); o.z = f2bf(v.z); o.w = f2bf(v.w);
        ((ushort4*)(arr ? Kb : Qb))[i] = o;
    } else {
        int g = (wg - 5120) * 256 + tid;        // 0 .. 524287
        int h = g >> 16;
        int d = (g >> 10) & 63;
        int s = g & 1023;
        int t = s >> 5, q = (s >> 3) & 3, j = s & 7;
        int src_s = (t << 5) + (q << 2) + (j & 3) + ((j >> 2) << 4);
        VTi[g] = f2bf(V[(((size_t)h << 10) + src_s) * Dn + d]);
    }
}

// ---------------------------------------------------------------------------
// Kernel C: lean fused attention. S^T formulation, no softmax offset
// (scores bounded ~|74|, exp stays in f32/bf16 range; normalization cancels).
// Grid (S/16, H), 256 threads = 4 waves; wave w: k in [w*256,(w+1)*256),
// 8 tiles of 32, explicit 2-deep pipeline on K + bias loads.
// __launch_bounds__(256,4): VGPR<=128, 4 WGs/CU = 16 waves/CU.
// ---------------------------------------------------------------------------
__global__ __launch_bounds__(256, 4) void attn_kernel(
    const u16* __restrict__ Qb, const u16* __restrict__ Kb, const u16* __restrict__ VTi,
    const u16* __restrict__ Bb, float* __restrict__ out)
{
    __shared__ float sO[4][16][68];             // 17.4 KB, padded stride
    __shared__ float sL[4][16];

    const int tid  = threadIdx.x;
    const int h    = blockIdx.y;
    const int q0   = blockIdx.x * 16;
    const int wave = tid >> 6;
    const int lane = tid & 63;
    const int quad = lane >> 4;
    const int l16  = lane & 15;

    const u16* Qh = Qb  + (size_t)h * Sn * Dn;
    const u16* Kh = Kb  + (size_t)h * Sn * Dn;
    const u16* Vh = VTi + (size_t)h * Dn * Sn;
    const u16* Bh = Bb  + ((size_t)(h * Sn + q0 + l16)) * Sn;   // row q0+l16
    const float scale = 0.08838834764831845f;   // 1/sqrt(2*64)

    // Persistent Q B-fragments: B[n=l16][k=quad*8+j]
    const bf16x8 bQ0 = *(const bf16x8*)(Qh + (q0 + l16) * Dn + quad * 8);
    const bf16x8 bQ1 = *(const bf16x8*)(Qh + (q0 + l16) * Dn + 32 + quad * 8);

    f32x4 O0 = {0.f, 0.f, 0.f, 0.f}, O1 = O0, O2 = O0, O3 = O0;
    float l_r = 0.f;

    const int kbase = wave * 256;
    const u16* krb = Kh + (size_t)l16 * Dn + quad * 8;   // + k0*Dn per tile
    const u16* vrb = Vh + quad * 8;                      // + l16*Sn rows, + k0

    // 2-deep pipeline registers (K + bias prefetched one tile ahead)
    bf16x8 cK[2][4];
    h16x4  cB[2][2];

    {   // preload tile 0
        const u16* kr = krb + (size_t)kbase * Dn;
        cK[0][0] = *(const bf16x8*)(kr);
        cK[0][1] = *(const bf16x8*)(kr + 32);
        cK[0][2] = *(const bf16x8*)(kr + 16 * Dn);
        cK[0][3] = *(const bf16x8*)(kr + 16 * Dn + 32);
        cB[0][0] = *(const h16x4*)(Bh + kbase + quad * 4);
        cB[0][1] = *(const h16x4*)(Bh + kbase + 16 + quad * 4);
    }

#pragma unroll
    for (int t = 0; t < 8; t++) {
        const int cur = t & 1, nxt = cur ^ 1;
        const int k0 = kbase + t * 32;

        if (t < 7) {   // prefetch next tile's K + bias
            const int kn = k0 + 32;
            const u16* kr = krb + (size_t)kn * Dn;
            cK[nxt][0] = *(const bf16x8*)(kr);
            cK[nxt][1] = *(const bf16x8*)(kr + 32);
            cK[nxt][2] = *(const bf16x8*)(kr + 16 * Dn);
            cK[nxt][3] = *(const bf16x8*)(kr + 16 * Dn + 32);
            cB[nxt][0] = *(const h16x4*)(Bh + kn + quad * 4);
            cB[nxt][1] = *(const h16x4*)(Bh + kn + 16 + quad * 4);
        }

        // V B-fragments for current tile (issued before QK compute)
        const u16* vr = vrb + k0;
        const bf16x8 bV0 = *(const bf16x8*)(vr + (size_t)(l16)      * Sn);
        const bf16x8 bV1 = *(const bf16x8*)(vr + (size_t)(16 + l16) * Sn);
        const bf16x8 bV2 = *(const bf16x8*)(vr + (size_t)(32 + l16) * Sn);
        const bf16x8 bV3 = *(const bf16x8*)(vr + (size_t)(48 + l16) * Sn);

        f32x4 s0 = {0.f, 0.f, 0.f, 0.f}, s1 = s0;
        s0 = __builtin_amdgcn_mfma_f32_16x16x32_bf16(cK[cur][0], bQ0, s0, 0, 0, 0);
        s0 = __builtin_amdgcn_mfma_f32_16x16x32_bf16(cK[cur][1], bQ1, s0, 0, 0, 0);
        s1 = __builtin_amdgcn_mfma_f32_16x16x32_bf16(cK[cur][2], bQ0, s1, 0, 0, 0);
        s1 = __builtin_amdgcn_mfma_f32_16x16x32_bf16(cK[cur][3], bQ1, s1, 0, 0, 0);

        bf16x8 aP;
#pragma unroll
        for (int r = 0; r < 4; r++) {
            const float p0 = __expf(fmaf(s0[r], scale, (float)cB[cur][0][r]));
            const float p1 = __expf(fmaf(s1[r], scale, (float)cB[cur][1][r]));
            l_r += p0 + p1;
            aP[r]     = (short)f2bf(p0);
            aP[4 + r] = (short)f2bf(p1);
        }

        O0 = __builtin_amdgcn_mfma_f32_16x16x32_bf16(aP, bV0, O0, 0, 0, 0);
        O1 = __builtin_amdgcn_mfma_f32_16x16x32_bf16(aP, bV1, O1, 0, 0, 0);
        O2 = __builtin_amdgcn_mfma_f32_16x16x32_bf16(aP, bV2, O2, 0, 0, 0);
        O3 = __builtin_amdgcn_mfma_f32_16x16x32_bf16(aP, bV3, O3, 0, 0, 0);
    }

    // l reduction (row = l16, sum across quads) + cross-wave combine
    l_r += __shfl_xor(l_r, 16, 64);
    l_r += __shfl_xor(l_r, 32, 64);
    if (lane < 16) sL[wave][lane] = l_r;

#pragma unroll
    for (int r = 0; r < 4; r++) {
        sO[wave][quad * 4 + r][ 0 + l16] = O0[r];
        sO[wave][quad * 4 + r][16 + l16] = O1[r];
        sO[wave][quad * 4 + r][32 + l16] = O2[r];
        sO[wave][quad * 4 + r][48 + l16] = O3[r];
    }
    __syncthreads();

    const int row = tid >> 4;
    const int c4  = (tid & 15) * 4;
    float lg = 0.f;
#pragma unroll
    for (int w = 0; w < 4; w++) lg += sL[w][row];
    const float inv = 1.0f / lg;

    float acc[4];
#pragma unroll
    for (int c = 0; c < 4; c++) {
        acc[c] = 0.f;
#pragma unroll
        for (int w = 0; w < 4; w++) acc[c] += sO[w][row][c4 + c];
        acc[c] *= inv;
    }
    float4 ov = {acc[0], acc[1], acc[2], acc[3]};
    *(float4*)(out + ((size_t)(h * Sn + q0 + row)) * Dn + c4) = ov;
}

// ---------------------------------------------------------------------------
extern "C" void kernel_launch(void* const* d_in, const int* in_sizes, int n_in,
                              void* d_out, int out_size, void* d_ws, size_t ws_size,
                              hipStream_t stream) {
    const float* Q    = (const float*)d_in[0];
    const float* K    = (const float*)d_in[1];
    const float* V    = (const float*)d_in[2];
    const float* Dm   = (const float*)d_in[3];
    const float* Em   = (const float*)d_in[4];
    const int*   Mask = (const int*)d_in[5];
    const float* muD  = (const float*)d_in[6];
    const float* sgD  = (const float*)d_in[7];
    const float* bD   = (const float*)d_in[8];
    const float* muE  = (const float*)d_in[9];
    const float* sgE  = (const float*)d_in[10];
    const float* bE   = (const float*)d_in[11];
    const float* W1   = (const float*)d_in[12];
    const float* b1   = (const float*)d_in[13];
    const float* W2   = (const float*)d_in[14];
    const float* b2   = (const float*)d_in[15];

    // ws: tab 16 KB | Qb 1 MB | Kb 1 MB | VTi 1 MB | Bb 16 MB
    u32* tab = (u32*)d_ws;
    u16* Qb  = (u16*)((char*)d_ws + 2 * TN * 4);
    u16* Kb  = Qb + (size_t)Hn * Sn * Dn;
    u16* VTi = Kb + (size_t)Hn * Sn * Dn;
    u16* Bb  = VTi + (size_t)Hn * Sn * Dn;

    build_tables_kernel<<<2 * TN / 256, 256, 0, stream>>>(
        muD, sgD, bD, muE, sgE, bE, W1, b1, W2, b2, tab);

    prep_kernel<<<7168, 256, 0, stream>>>(Dm, Em, Mask, Q, K, V, tab,
                                          Bb, Qb, Kb, VTi);

    dim3 grid(Sn / 16, Hn);
    attn_kernel<<<grid, 256, 0, stream>>>(Qb, Kb, VTi, Bb, (float*)d_out);
}

// Round 6
// 179.226 us; speedup vs baseline: 1.0415x; 1.0415x over previous
//
#include <hip/hip_runtime.h>
#include <math.h>

// Shapes (fixed by the problem)
#define Hn 8
#define Sn 1024
#define Dn 64
#define KG 10

// Bias tables: dist in [0,10), energy in [0,5)
#define TN 2048
#define RD 10.25f
#define RE 5.125f

typedef __attribute__((ext_vector_type(8))) short bf16x8;
typedef __attribute__((ext_vector_type(4))) float f32x4;
typedef __attribute__((ext_vector_type(4))) _Float16 h16x4;
typedef unsigned short u16;
typedef unsigned int u32;

__device__ inline float bf2f(u16 u) {
    union { u32 i; float f; } v;
    v.i = ((u32)u) << 16;
    return v.f;
}

__device__ inline u16 f2bf(float f) {
    union { float f; u32 i; } v;
    v.f = f;
    u32 i = v.i;
    return (u16)((i + 0x7FFFu + ((i >> 16) & 1u)) >> 16);   // RNE
}

__device__ inline u16 f2h_bits(float f) {
    union { _Float16 h; u16 u; } cv;
    cv.h = (_Float16)f;                                     // v_cvt_f16_f32, RNE
    return cv.u;
}

// ---------------------------------------------------------------------------
// RBF (10 gaussians) -> 10x10 MLP (exact gelu) -> scalar, all f32.
// ---------------------------------------------------------------------------
__device__ float bias_eval(float x,
                           const float* __restrict__ mu, const float* __restrict__ sg,
                           const float* __restrict__ bb,
                           const float* __restrict__ W1, const float* __restrict__ b1,
                           const float* __restrict__ W2, const float* __restrict__ b2) {
    const float inv_s2pi = 0.39894228040143267794f;
    float psi[KG];
#pragma unroll
    for (int k = 0; k < KG; k++) {
        float s = sg[k];
        float z = (x + bb[k] - mu[k]) / s;
        psi[k] = __expf(-0.5f * z * z) * (inv_s2pi / s);
    }
    float out = b2[0];
#pragma unroll
    for (int l = 0; l < KG; l++) {
        float a = b1[l];
#pragma unroll
        for (int k = 0; k < KG; k++) a += psi[k] * W1[l * KG + k];
        float g = 0.5f * a * (1.0f + erff(a * 0.70710678118654752440f));
        out += g * W2[l];
    }
    return out;
}

// ---------------------------------------------------------------------------
// Kernel A: interpolation tables. Entry i: lo16 = bf16(f(x_i)),
// hi16 = bf16(f(x_{i+1}) - f(x_i)). [0,TN) dist, [TN,2TN) energy.
// ---------------------------------------------------------------------------
__global__ __launch_bounds__(256) void build_tables_kernel(
    const float* __restrict__ muD, const float* __restrict__ sgD, const float* __restrict__ bD,
    const float* __restrict__ muE, const float* __restrict__ sgE, const float* __restrict__ bE,
    const float* __restrict__ W1, const float* __restrict__ b1,
    const float* __restrict__ W2, const float* __restrict__ b2,
    u32* __restrict__ tab)
{
    int id = blockIdx.x * 256 + threadIdx.x;   // 0 .. 4095
    int which = (id >= TN);
    int idx = id & (TN - 1);
    float h = (which ? RE : RD) / (float)TN;
    float x0 = idx * h;
    float v0, v1;
    if (which) {
        v0 = bias_eval(x0,     muE, sgE, bE, W1, b1, W2, b2);
        v1 = bias_eval(x0 + h, muE, sgE, bE, W1, b1, W2, b2);
    } else {
        v0 = bias_eval(x0,     muD, sgD, bD, W1, b1, W2, b2);
        v1 = bias_eval(x0 + h, muD, sgD, bD, W1, b1, W2, b2);
    }
    tab[id] = (u32)f2bf(v0) | ((u32)f2bf(v1 - v0) << 16);
}

// ---------------------------------------------------------------------------
// Kernel B: small prepass.
//  WGs [0,1024)     : Q,K f32 -> bf16 (float4 granularity).
//  WGs [1024,1152)  : V -> bf16 transpose via LDS tile (coalesced both sides),
//                     layout [h][d][s'] with MFMA k-perm:
//                     s' = t*32+q*8+j  <->  s = t*32+q*4+(j&3)+16*(j>>2).
// ---------------------------------------------------------------------------
__global__ __launch_bounds__(256) void prep_kernel(
    const float* __restrict__ Q, const float* __restrict__ K, const float* __restrict__ V,
    u16* __restrict__ Qb, u16* __restrict__ Kb, u16* __restrict__ VTi)
{
    __shared__ float tile[64][68];
    const int wg = blockIdx.x, tid = threadIdx.x;

    if (wg < 1024) {
        int i = wg * 256 + tid;                  // 0 .. 262143 float4 units
        int arr = i >> 17;                        // 0 = Q, 1 = K
        i &= (1 << 17) - 1;
        float4 v = ((const float4*)(arr ? K : Q))[i];
        ushort4 o;
        o.x = f2bf(v.x); o.y = f2bf(v.y); o.z = f2bf(v.z); o.w = f2bf(v.w);
        ((ushort4*)(arr ? Kb : Qb))[i] = o;
    } else {
        const int b  = wg - 1024;                // 0..127
        const int h  = b >> 4;
        const int s0 = (b & 15) * 64;
        const int rr = tid >> 4, cc = (tid & 15) * 4;
        const float* Vh = V + ((size_t)h * Sn + s0) * Dn;
#pragma unroll
        for (int i = 0; i < 4; i++) {
            float4 v = *(const float4*)(Vh + (size_t)(i * 16 + rr) * Dn + cc);
            tile[i * 16 + rr][cc]     = v.x;
            tile[i * 16 + rr][cc + 1] = v.y;
            tile[i * 16 + rr][cc + 2] = v.z;
            tile[i * 16 + rr][cc + 3] = v.w;
        }
        __syncthreads();
        u16* dst = VTi + (size_t)h * Dn * Sn + s0;
#pragma unroll
        for (int i = 0; i < 4; i++) {
            const int d = i * 16 + rr;
            u16 tmp[4];
#pragma unroll
            for (int j2 = 0; j2 < 4; j2++) {
                int sp = cc + j2;                // s' in 0..63
                int q = (sp >> 3) & 3, j = sp & 7;
                int s = (sp & ~31) + q * 4 + (j & 3) + ((j >> 2) << 4);
                tmp[j2] = f2bf(tile[s][d]);
            }
            ushort4 o = {tmp[0], tmp[1], tmp[2], tmp[3]};
            *(ushort4*)(dst + (size_t)d * Sn + cc) = o;
        }
    }
}

// ---------------------------------------------------------------------------
// Kernel C: fused condense + flash attention.
// Grid (S/16, H), 256 threads = 4 waves.
// Phase 1: WG streams ITS OWN 16 rows of D/E/mask (coalesced float4, one-pass
//          coverage of the whole 100.7 MB across the grid), condenses through
//          LDS tables into a 16x1024 fp16 LDS bias tile (masked -> -60).
// Phase 2: r5's lean S^T flash loop; bias via ds_read_b64 (stride 1032 pad ->
//          2-way conflicts, free). No softmax offset (scores bounded ~|70|,
//          exp stays in range; normalization cancels).
// LDS: 33 KB bias + union(16 KB tables, 17.7 KB epilogue) ~= 50.7 KB.
// ---------------------------------------------------------------------------
__global__ __launch_bounds__(256, 4) void attn_kernel(
    const u16* __restrict__ Qb, const u16* __restrict__ Kb, const u16* __restrict__ VTi,
    const float* __restrict__ Dm, const float* __restrict__ Em, const int* __restrict__ Mk,
    const u32* __restrict__ gtab, float* __restrict__ out)
{
    __shared__ u16 sBias[16][1032];              // 33 KB, padded stride
    __shared__ union {
        u32 tab[2 * TN];                         // phase 1: bias tables (16 KB)
        struct { float O[4][16][68]; float L[4][16]; } f;   // epilogue (17.7 KB)
    } sU;

    const int tid  = threadIdx.x;
    const int h    = blockIdx.y;
    const int q0   = blockIdx.x * 16;

    {   // stage tables: 1024 uint4 over 256 threads
        const uint4* g4 = (const uint4*)gtab;
        uint4* s4 = (uint4*)sU.tab;
#pragma unroll
        for (int i = 0; i < 4; i++) s4[tid + 256 * i] = g4[tid + 256 * i];
    }
    __syncthreads();

    // ---- Phase 1: condense D/E/mask rows q0..q0+15 into sBias ----
    {
        const float invhD = (float)TN / RD;
        const float invhE = (float)TN / RE;
        const int prow = tid >> 4;               // 0..15
        const int pcb  = (tid & 15) * 4;         // col base; +i*64 sweeps row
        const size_t roff = ((size_t)h * Sn + q0 + prow) * Sn + pcb;
        const float* Dr = Dm + roff;
        const float* Er = Em + roff;
        const int*   Mr = Mk + roff;

#pragma unroll 4
        for (int i = 0; i < 16; i++) {
            const int c = pcb + i * 64;
            const float4 d4 = *(const float4*)(Dr + i * 64);
            const float4 e4 = *(const float4*)(Er + i * 64);
            const int4   m4 = *(const int4*)(Mr + i * 64);
            const float dv[4] = {d4.x, d4.y, d4.z, d4.w};
            const float ev[4] = {e4.x, e4.y, e4.z, e4.w};
            const int   mv[4] = {m4.x, m4.y, m4.z, m4.w};
            u16 ob[4];
#pragma unroll
            for (int j = 0; j < 4; j++) {
                float tf = dv[j] * invhD;
                int ix = min((int)tf, TN - 1);
                float fr = tf - (float)ix;
                u32 p = sU.tab[ix];
                float vD = fmaf(bf2f((u16)(p >> 16)), fr, bf2f((u16)p));

                tf = ev[j] * invhE;
                ix = min((int)tf, TN - 1);
                fr = tf - (float)ix;
                p = sU.tab[TN + ix];
                float vE = fmaf(bf2f((u16)(p >> 16)), fr, bf2f((u16)p));

                float v = fminf(fmaxf(vD + vE, -60.f), 64.f);
                v = (mv[j] == 0) ? -60.f : v;
                ob[j] = f2h_bits(v);
            }
            *(ushort4*)(&sBias[prow][c]) = *(const ushort4*)ob;
        }
    }
    __syncthreads();

    // ---- Phase 2: flash attention over LDS bias ----
    const int wave = tid >> 6;
    const int lane = tid & 63;
    const int quad = lane >> 4;
    const int l16  = lane & 15;

    const u16* Qh = Qb  + (size_t)h * Sn * Dn;
    const u16* Kh = Kb  + (size_t)h * Sn * Dn;
    const u16* Vh = VTi + (size_t)h * Dn * Sn;
    const float scale = 0.08838834764831845f;    // 1/sqrt(2*64)

    const bf16x8 bQ0 = *(const bf16x8*)(Qh + (q0 + l16) * Dn + quad * 8);
    const bf16x8 bQ1 = *(const bf16x8*)(Qh + (q0 + l16) * Dn + 32 + quad * 8);

    f32x4 O0 = {0.f, 0.f, 0.f, 0.f}, O1 = O0, O2 = O0, O3 = O0;
    float l_r = 0.f;

    const int kbase = wave * 256;
    const u16* krb = Kh + (size_t)l16 * Dn + quad * 8;
    const u16* vrb = Vh + quad * 8;

    bf16x8 cK[2][4];     // 2-deep K prefetch (L2-resident stream)
    {
        const u16* kr = krb + (size_t)kbase * Dn;
        cK[0][0] = *(const bf16x8*)(kr);
        cK[0][1] = *(const bf16x8*)(kr + 32);
        cK[0][2] = *(const bf16x8*)(kr + 16 * Dn);
        cK[0][3] = *(const bf16x8*)(kr + 16 * Dn + 32);
    }

#pragma unroll
    for (int t = 0; t < 8; t++) {
        const int cur = t & 1, nxt = cur ^ 1;
        const int k0 = kbase + t * 32;

        if (t < 7) {
            const u16* kr = krb + (size_t)(k0 + 32) * Dn;
            cK[nxt][0] = *(const bf16x8*)(kr);
            cK[nxt][1] = *(const bf16x8*)(kr + 32);
            cK[nxt][2] = *(const bf16x8*)(kr + 16 * Dn);
            cK[nxt][3] = *(const bf16x8*)(kr + 16 * Dn + 32);
        }

        const u16* vr = vrb + k0;
        const bf16x8 bV0 = *(const bf16x8*)(vr + (size_t)(l16)      * Sn);
        const bf16x8 bV1 = *(const bf16x8*)(vr + (size_t)(16 + l16) * Sn);
        const bf16x8 bV2 = *(const bf16x8*)(vr + (size_t)(32 + l16) * Sn);
        const bf16x8 bV3 = *(const bf16x8*)(vr + (size_t)(48 + l16) * Sn);

        // bias from LDS (row = qrow = l16, cols = the 4 accumulator regs)
        const h16x4 cb0 = *(const h16x4*)(&sBias[l16][k0 + quad * 4]);
        const h16x4 cb1 = *(const h16x4*)(&sBias[l16][k0 + 16 + quad * 4]);

        f32x4 s0 = {0.f, 0.f, 0.f, 0.f}, s1 = s0;
        s0 = __builtin_amdgcn_mfma_f32_16x16x32_bf16(cK[cur][0], bQ0, s0, 0, 0, 0);
        s0 = __builtin_amdgcn_mfma_f32_16x16x32_bf16(cK[cur][1], bQ1, s0, 0, 0, 0);
        s1 = __builtin_amdgcn_mfma_f32_16x16x32_bf16(cK[cur][2], bQ0, s1, 0, 0, 0);
        s1 = __builtin_amdgcn_mfma_f32_16x16x32_bf16(cK[cur][3], bQ1, s1, 0, 0, 0);

        bf16x8 aP;
#pragma unroll
        for (int r = 0; r < 4; r++) {
            const float p0 = __expf(fmaf(s0[r], scale, (float)cb0[r]));
            const float p1 = __expf(fmaf(s1[r], scale, (float)cb1[r]));
            l_r += p0 + p1;
            aP[r]     = (short)f2bf(p0);
            aP[4 + r] = (short)f2bf(p1);
        }

        O0 = __builtin_amdgcn_mfma_f32_16x16x32_bf16(aP, bV0, O0, 0, 0, 0);
        O1 = __builtin_amdgcn_mfma_f32_16x16x32_bf16(aP, bV1, O1, 0, 0, 0);
        O2 = __builtin_amdgcn_mfma_f32_16x16x32_bf16(aP, bV2, O2, 0, 0, 0);
        O3 = __builtin_amdgcn_mfma_f32_16x16x32_bf16(aP, bV3, O3, 0, 0, 0);
    }

    // l reduction (row = l16, sum across quads) + cross-wave combine
    l_r += __shfl_xor(l_r, 16, 64);
    l_r += __shfl_xor(l_r, 32, 64);
    __syncthreads();                 // all phase-2 table use done; reuse union
    if (lane < 16) sU.f.L[wave][lane] = l_r;
#pragma unroll
    for (int r = 0; r < 4; r++) {
        sU.f.O[wave][quad * 4 + r][ 0 + l16] = O0[r];
        sU.f.O[wave][quad * 4 + r][16 + l16] = O1[r];
        sU.f.O[wave][quad * 4 + r][32 + l16] = O2[r];
        sU.f.O[wave][quad * 4 + r][48 + l16] = O3[r];
    }
    __syncthreads();

    const int row = tid >> 4;
    const int c4  = (tid & 15) * 4;
    float lg = 0.f;
#pragma unroll
    for (int w = 0; w < 4; w++) lg += sU.f.L[w][row];
    const float inv = 1.0f / lg;

    float acc[4];
#pragma unroll
    for (int c = 0; c < 4; c++) {
        acc[c] = 0.f;
#pragma unroll
        for (int w = 0; w < 4; w++) acc[c] += sU.f.O[w][row][c4 + c];
        acc[c] *= inv;
    }
    float4 ov = {acc[0], acc[1], acc[2], acc[3]};
    *(float4*)(out + ((size_t)(h * Sn + q0 + row)) * Dn + c4) = ov;
}

// ---------------------------------------------------------------------------
extern "C" void kernel_launch(void* const* d_in, const int* in_sizes, int n_in,
                              void* d_out, int out_size, void* d_ws, size_t ws_size,
                              hipStream_t stream) {
    const float* Q    = (const float*)d_in[0];
    const float* K    = (const float*)d_in[1];
    const float* V    = (const float*)d_in[2];
    const float* Dm   = (const float*)d_in[3];
    const float* Em   = (const float*)d_in[4];
    const int*   Mask = (const int*)d_in[5];
    const float* muD  = (const float*)d_in[6];
    const float* sgD  = (const float*)d_in[7];
    const float* bD   = (const float*)d_in[8];
    const float* muE  = (const float*)d_in[9];
    const float* sgE  = (const float*)d_in[10];
    const float* bE   = (const float*)d_in[11];
    const float* W1   = (const float*)d_in[12];
    const float* b1   = (const float*)d_in[13];
    const float* W2   = (const float*)d_in[14];
    const float* b2   = (const float*)d_in[15];

    // ws: tab 16 KB | Qb 1 MB | Kb 1 MB | VTi 1 MB
    u32* tab = (u32*)d_ws;
    u16* Qb  = (u16*)((char*)d_ws + 2 * TN * 4);
    u16* Kb  = Qb + (size_t)Hn * Sn * Dn;
    u16* VTi = Kb + (size_t)Hn * Sn * Dn;

    build_tables_kernel<<<2 * TN / 256, 256, 0, stream>>>(
        muD, sgD, bD, muE, sgE, bE, W1, b1, W2, b2, tab);

    prep_kernel<<<1152, 256, 0, stream>>>(Q, K, V, Qb, Kb, VTi);

    dim3 grid(Sn / 16, Hn);
    attn_kernel<<<grid, 256, 0, stream>>>(Qb, Kb, VTi, Dm, Em, Mask, tab,
                                          (float*)d_out);
}